// Round 7
// baseline (249.967 us; speedup 1.0000x reference)
//
#include <hip/hip_runtime.h>

#define L 1024
#define NB 32
#define GRIDY 32                        // y-blocks per batch
#define CHROWS 16                       // rows per chunk
#define NPART (NB * GRIDY)

// ---------------- Kernel 1: per-batch lens + scale ---------------------------
__global__ void prep_kernel(const int* __restrict__ mask,
                            float* __restrict__ scale,   // ws: 32 floats
                            int* __restrict__ lens_out) {// ws: 32 ints
    const int b = blockIdx.x;
    const int t = threadIdx.x;
    const int* mrow = mask + b * L;
    int s = 0;
    for (int j = t; j < L; j += 256) s += mrow[j];
    for (int off = 32; off > 0; off >>= 1) s += __shfl_down(s, off, 64);
    __shared__ int wsum[4];
    if ((t & 63) == 0) wsum[t >> 6] = s;
    __syncthreads();
    if (t == 0) {
        const int total = wsum[0] + wsum[1] + wsum[2] + wsum[3];
        const int lens = total - 2;
        lens_out[b] = lens;
        float sc = 0.0f;
        if (lens > 0) sc = 1.0f / (32.0f * (float)lens * (float)lens);
        scale[b] = sc;
    }
}

// ---------------- Kernel 2: masked |T - A^2| partial sums --------------------
// A[i][j] = input[i+1][j+1]; contribution |T[i][j] - A[i][j]^2| for i,j < len.
// Input row loaded as ALIGNED float4 at col j (gives A cols j-1..j+2) plus one
// scalar at j+4 -> 3 VMEM per 32B useful, all aligned.
__device__ __forceinline__ float quad_contrib(const float* __restrict__ trow,
                                              const float* __restrict__ irow,
                                              int j, int len) {
    const float4 tv = *reinterpret_cast<const float4*>(trow + j);  // T cols j..j+3
    const float4 iv = *reinterpret_cast<const float4*>(irow + j);  // in cols j..j+3
    const float nx = irow[j + 4];                                  // in col j+4 (A col j+3)
    const float c0 = fabsf(tv.x - iv.y * iv.y);
    const float c1 = fabsf(tv.y - iv.z * iv.z);
    const float c2 = fabsf(tv.z - iv.w * iv.w);
    const float c3 = fabsf(tv.w - nx * nx);
    if (j + 4 <= len) return c0 + c1 + c2 + c3;    // all 4 cols < len
    float r = 0.0f;
    if (j + 0 < len) r += c0;
    if (j + 1 < len) r += c1;
    if (j + 2 < len) r += c2;
    return r;                                       // col j+3 >= len here
}

__global__ void __launch_bounds__(256)
loss_kernel(const float* __restrict__ input,
            const float* __restrict__ target,
            const float* __restrict__ scale,
            const int* __restrict__ lens,
            float* __restrict__ partials) {  // ws: NPART floats
    const int b = blockIdx.x;
    const int len = lens[b];
    const int t = threadIdx.x;
    const int rsel = t >> 7;             // 0/1: which row of the pair (wave-uniform)
    const int j0 = (t & 127) * 4;        // column base, 0..508

    const size_t slab = (size_t)b * L * L;
    const float* __restrict__ tg = target + slab;
    const float* __restrict__ in = input + slab;

    float acc = 0.0f;

    for (int c = blockIdx.y; c * CHROWS < len; c += GRIDY) {
        const int base = c * CHROWS;
#pragma unroll
        for (int s = 0; s < CHROWS / 2; ++s) {
            const int i = base + 2 * s + rsel;
            if (i < len && j0 < len) {
                const float* trow = tg + (size_t)i * L;
                const float* irow = in + (size_t)(i + 1) * L;
                acc += quad_contrib(trow, irow, j0, len);
                const int j1 = j0 + 512;
                if (j1 < len) acc += quad_contrib(trow, irow, j1, len);
            }
        }
    }

    // block reduce: wave shfl then LDS
    for (int off = 32; off > 0; off >>= 1) acc += __shfl_down(acc, off, 64);
    __shared__ float wsum[4];
    if ((t & 63) == 0) wsum[t >> 6] = acc;
    __syncthreads();
    if (t == 0) {
        // ALWAYS write (d_ws re-poisoned before every timed launch)
        partials[b * GRIDY + blockIdx.y] = (wsum[0] + wsum[1] + wsum[2] + wsum[3]) * scale[b];
    }
}

// ---------------- Kernel 3: final sum of partials ----------------------------
__global__ void __launch_bounds__(256)
reduce_kernel(const float* __restrict__ partials, float* __restrict__ out) {
    const int t = threadIdx.x;
    float s = 0.0f;
    for (int k = t; k < NPART; k += 256) s += partials[k];
    for (int off = 32; off > 0; off >>= 1) s += __shfl_down(s, off, 64);
    __shared__ float wsum[4];
    if ((t & 63) == 0) wsum[t >> 6] = s;
    __syncthreads();
    if (t == 0) out[0] = wsum[0] + wsum[1] + wsum[2] + wsum[3];
}

extern "C" void kernel_launch(void* const* d_in, const int* in_sizes, int n_in,
                              void* d_out, int out_size, void* d_ws, size_t ws_size,
                              hipStream_t stream) {
    const float* input  = (const float*)d_in[0];   // (32,1024,1024) f32
    const int*   mask   = (const int*)d_in[1];     // (32,1024) i32
    const float* target = (const float*)d_in[2];   // (32,1024,1024) f32
    float* out = (float*)d_out;

    float* scale    = (float*)d_ws;                               // 32 floats
    int*   lens     = (int*)((char*)d_ws + 32 * sizeof(float));   // 32 ints
    float* partials = (float*)((char*)d_ws + 64 * sizeof(float)); // NPART floats

    prep_kernel<<<dim3(NB), dim3(256), 0, stream>>>(mask, scale, lens);
    loss_kernel<<<dim3(NB, GRIDY), dim3(256), 0, stream>>>(input, target, scale, lens, partials);
    reduce_kernel<<<dim3(1), dim3(256), 0, stream>>>(partials, out);
}